// Round 5
// baseline (82.820 us; speedup 1.0000x reference)
//
#include <hip/hip_runtime.h>
#include <math.h>

#define TPB 256
#define IB 64
#define EPSF 1e-15f

typedef float v2f __attribute__((ext_vector_type(2)));

// Fused prep + O(n^2) pair kernel, packed-f32 (v_pk_*) inner loop.
// Rs = (g1+log y)/(h*sqrt(2 ln 2)) so exp(-0.5*((R_i-R_j)/h)^2) = exp2(-dr^2).
// A_j = sum_i d_i*e;  L*Phi = 0.5*L + copysign(L,dr)*(0.5-u),
// u = upper-tail Q via A&S 7.1.25 3-term erfc (|eps|<=2.5e-5), reusing the
// SAME exp2. 0.5*sum(L) over this block's span folded in once (spans
// partition i, so block sums telescope to 0.5*sum_all L).
__global__ __launch_bounds__(TPB, 8) void pair_kernel(
    const float* __restrict__ m_z, const float* __restrict__ y,
    const float* __restrict__ delta, float2* __restrict__ P,
    float* __restrict__ out, float inv_hk, int n, int span) {
    __shared__ float4 sRd[128];   // {R_2k, R_2k+1, d_2k, d_2k+1}
    __shared__ float2 sL2[128];   // {L_2k, L_2k+1}
    __shared__ float sLtot;
    const int tid = threadIdx.x;
    const int j = blockIdx.x * TPB + tid;
    const float2* __restrict__ mz2 = (const float2*)m_z;

    if (j == 0 && blockIdx.y == 0) out[0] = 0.0f;  // harness poisons d_out

    const float2 gj = mz2[j];
    const float Rj = (gj.x + __logf(y[j])) * inv_hk;

    // prep this block's i-span into LDS (span <= 256)
    const int ibase = blockIdx.y * span;
    if (tid < span) {
        const int i = ibase + tid;
        const float2 g = mz2[i];
        float* s = (float*)sRd;
        const int pk = tid >> 1, hf = tid & 1;
        s[4 * pk + hf]     = (g.x + __logf(y[i])) * inv_hk;
        s[4 * pk + 2 + hf] = delta[i];
        ((float*)sL2)[tid] = __expf(g.y - g.x);
    }
    __syncthreads();
    if (tid < 64) {  // wave 0: sum L over the span
        float s = 0.0f;
        for (int t = tid; t < span; t += 64) s += ((float*)sL2)[t];
        for (int o = 32; o > 0; o >>= 1) s += __shfl_down(s, o, 64);
        if (tid == 0) sLtot = s;
    }
    __syncthreads();

    const v2f Rj2   = {Rj, Rj};
    const v2f C1v   = {0.3916993f, 0.3916993f};   // 0.3326783*sqrt(2 ln 2)
    const v2f A3v   = {0.3739278f, 0.3739278f};   // pre-halved A&S coeffs
    const v2f A2v   = {-0.0479399f, -0.0479399f};
    const v2f A1v   = {0.1740121f, 0.1740121f};
    const v2f ONEv  = {1.0f, 1.0f};
    const v2f HALFv = {0.5f, 0.5f};

    v2f accA = {0.0f, 0.0f};
    v2f accB = {0.5f * sLtot, 0.0f};
    const int m = span >> 1;
#pragma unroll 4
    for (int k = 0; k < m; ++k) {
        const float4 rd = sRd[k];                 // broadcast LDS reads
        const float2 ll = sL2[k];
        const v2f Ri = {rd.x, rd.y};
        const v2f Di = {rd.z, rd.w};
        const v2f Li = {ll.x, ll.y};
        const v2f dr = Ri - Rj2;                              // v_pk_add (neg)
        const v2f q  = dr * dr;                               // v_pk_mul
        const v2f e  = {__builtin_amdgcn_exp2f(-q.x),         // exp(-drt^2/2)
                        __builtin_amdgcn_exp2f(-q.y)};
        const v2f ad = __builtin_elementwise_abs(dr);
        const v2f ta = __builtin_elementwise_fma(C1v, ad, ONEv);
        const v2f t  = {__builtin_amdgcn_rcpf(ta.x), __builtin_amdgcn_rcpf(ta.y)};
        const v2f u  = t * __builtin_elementwise_fma(
                               t, __builtin_elementwise_fma(t, A3v, A2v), A1v) * e;
        const v2f g  = HALFv - u;
        const v2f sl = __builtin_elementwise_copysign(Li, dr);
        accA = __builtin_elementwise_fma(Di, e, accA);        // v_pk_fma
        accB = __builtin_elementwise_fma(sl, g, accB);        // v_pk_fma
    }
    P[(size_t)blockIdx.y * n + j] = make_float2(accA.x + accA.y, accB.x + accB.y);
}

// out = (1/n) * sum_j d_j * (R_j - g2_j - log(c1*A_j + eps) + log(invn*B_j + eps))
__global__ __launch_bounds__(TPB) void finalize_kernel(
    const float2* __restrict__ P, const float* __restrict__ m_z,
    const float* __restrict__ y, const float* __restrict__ delta,
    float* __restrict__ out, float c1, float invn, int n) {
    const int j = blockIdx.x * TPB + threadIdx.x;
    float sa = 0.0f, sb = 0.0f;
    for (int b = 0; b < IB; ++b) {               // coalesced float2 reads
        const float2 v = P[(size_t)b * n + j];
        sa += v.x;
        sb += v.y;
    }
    const float d = delta[j];
    const float R = m_z[2 * j] + __logf(y[j]);
    float term = d * (R - m_z[2 * j + 1] - __logf(fmaf(c1, sa, EPSF))
                                         + __logf(fmaf(invn, sb, EPSF)));
    for (int o = 32; o > 0; o >>= 1) term += __shfl_down(term, o, 64);
    __shared__ float wsum[TPB / 64];
    if ((threadIdx.x & 63) == 0) wsum[threadIdx.x >> 6] = term;
    __syncthreads();
    if (threadIdx.x == 0) {
        float ssum = 0.0f;
        for (int w = 0; w < TPB / 64; ++w) ssum += wsum[w];
        atomicAdd(out, ssum * invn);
    }
}

extern "C" void kernel_launch(void* const* d_in, const int* in_sizes, int n_in,
                              void* d_out, int out_size, void* d_ws, size_t ws_size,
                              hipStream_t stream) {
    const float* m_z   = (const float*)d_in[0];   // (n,2)
    const float* y     = (const float*)d_in[1];   // (n,1)
    const float* delta = (const float*)d_in[2];   // (n,1)
    float* out = (float*)d_out;
    const int n = in_sizes[1];                    // 8192

    float2* P = (float2*)d_ws;                    // IB * n * 8 B = 4 MB

    const double h = 1.3 * pow((double)n, -0.2);
    const double kk = 1.1774100225154747;         // sqrt(2 ln 2)
    const float inv_hk = (float)(1.0 / (h * kk));
    const float c1 = (float)(0.3989422804014327 / ((double)n * h)); // INV_SQRT_2PI/(n*h)
    const float invn = 1.0f / (float)n;
    const int span = n / IB;                      // 128

    const int nblk = (n + TPB - 1) / TPB;         // 32
    dim3 grid(nblk, IB);                          // 2048 blocks = 8/CU
    pair_kernel<<<grid, TPB, 0, stream>>>(m_z, y, delta, P, out, inv_hk, n, span);
    finalize_kernel<<<nblk, TPB, 0, stream>>>(P, m_z, y, delta, out, c1, invn, n);
}